// Round 1
// baseline (3091.855 us; speedup 1.0000x reference)
//
#include <hip/hip_runtime.h>

#define BLOCK 256

// ---------------- degree / norm ----------------
__global__ void deg_kernel(const int* __restrict__ src, const int* __restrict__ dst,
                           float* __restrict__ degO, float* __restrict__ degI, int E) {
    int e = blockIdx.x * blockDim.x + threadIdx.x;
    if (e < E) {
        atomicAdd(&degO[src[e]], 1.0f);
        atomicAdd(&degI[dst[e]], 1.0f);
    }
}

__global__ void norm_kernel(float* __restrict__ d, int n) {
    int i = blockIdx.x * blockDim.x + threadIdx.x;
    if (i < n) d[i] = rsqrtf(fmaxf(d[i], 1.0f));
}

// ---------------- edge scatter-add ----------------
// out[dst[e]*D + d] += in[src[e]*D + d] * nodeScale[src[e]] * edgeScale[e]
template <int D>
__global__ void scatter_kernel(const float* __restrict__ in, float* __restrict__ out,
                               const int* __restrict__ src, const int* __restrict__ dst,
                               const float* __restrict__ nodeScale,
                               const float* __restrict__ edgeScale, int E) {
    int gid = blockIdx.x * blockDim.x + threadIdx.x;
    int e = gid / D;
    int d = gid % D;
    if (e < E) {
        int s = src[e];
        float v = in[s * D + d];
        if (nodeScale) v *= nodeScale[s];
        if (edgeScale) v *= edgeScale[e];
        atomicAdd(&out[dst[e] * D + d], v);
    }
}

// ---------------- dense GEMM (one thread per output element) ----------------
// C[row,col] = (sum_k A[row,k]*W[k,col]) * rowScaleIn[row]   (optional)
// then optionally: * rowScaleOut[row] + bias[col], optional relu
__global__ void gemm_kernel(const float* __restrict__ A, const float* __restrict__ W,
                            const float* __restrict__ rowScaleIn,
                            const float* __restrict__ rowScaleOut,
                            const float* __restrict__ bias,
                            float* __restrict__ C, int N, int K1, int K2, int relu) {
    int gid = blockIdx.x * blockDim.x + threadIdx.x;
    int col = gid % K2;
    int row = gid / K2;
    if (row >= N) return;
    const float* a = A + (size_t)row * K1;
    float acc = 0.0f;
    for (int k = 0; k < K1; ++k) acc += a[k] * W[k * K2 + col];
    if (rowScaleIn) acc *= rowScaleIn[row];
    if (rowScaleOut) acc = acc * rowScaleOut[row] + bias[col];
    if (relu) acc = fmaxf(acc, 0.0f);
    C[gid] = acc;
}

// ---------------- epilogue after gc aggregation ----------------
// out[v,d] = (agg[v,d] * normI[v] + bias[d])  (relu optional)
__global__ void epi_kernel(const float* __restrict__ agg, const float* __restrict__ normI,
                           const float* __restrict__ bias, float* __restrict__ out,
                           int N, int D, int relu) {
    int gid = blockIdx.x * blockDim.x + threadIdx.x;
    int d = gid % D;
    int v = gid / D;
    if (v < N) {
        float x = agg[gid] * normI[v] + bias[d];
        out[gid] = relu ? fmaxf(x, 0.0f) : x;
    }
}

__global__ void relu_kernel(float* __restrict__ x, int n) {
    int i = blockIdx.x * blockDim.x + threadIdx.x;
    if (i < n) x[i] = fmaxf(x[i], 0.0f);
}

static inline int nblk(long n) { return (int)((n + BLOCK - 1) / BLOCK); }

extern "C" void kernel_launch(void* const* d_in, const int* in_sizes, int n_in,
                              void* d_out, int out_size, void* d_ws, size_t ws_size,
                              hipStream_t stream) {
    const float* x    = (const float*)d_in[0];
    const float* efet = (const float*)d_in[1];
    const int*   src  = (const int*)d_in[2];
    const int*   dst  = (const int*)d_in[3];
    const float* W1 = (const float*)d_in[4];  const float* b1 = (const float*)d_in[5];
    const float* W2 = (const float*)d_in[6];  const float* b2 = (const float*)d_in[7];
    const float* W3 = (const float*)d_in[8];  const float* b3 = (const float*)d_in[9];
    const float* W4 = (const float*)d_in[10]; const float* b4 = (const float*)d_in[11];
    const float* W5 = (const float*)d_in[12]; const float* b5 = (const float*)d_in[13];
    float* out = (float*)d_out;

    const int N = in_sizes[0] / 16;
    const int E = in_sizes[2];

    float* ws    = (float*)d_ws;
    float* normO = ws;                    // N
    float* normI = ws + N;                // N
    float* A = ws + 2 * (size_t)N;        // 128N floats
    float* B = A + 128 * (size_t)N;       // 256N floats
    float* C = B + 256 * (size_t)N;       // 256N floats

    // ---- degrees -> norms ----
    hipMemsetAsync(normO, 0, 2 * (size_t)N * sizeof(float), stream);
    deg_kernel<<<nblk(E), BLOCK, 0, stream>>>(src, dst, normO, normI, E);
    norm_kernel<<<nblk(2L * N), BLOCK, 0, stream>>>(normO, 2 * N);

    // ---- Layer 1: aggregate-first (16-dim), then GEMM 16->256, then ewa ----
    hipMemsetAsync(A, 0, (size_t)N * 16 * sizeof(float), stream);
    scatter_kernel<16><<<nblk((long)E * 16), BLOCK, 0, stream>>>(x, A, src, dst, normO, nullptr, E);
    gemm_kernel<<<nblk((long)N * 256), BLOCK, 0, stream>>>(A, W1, nullptr, normI, b1, B, N, 16, 256, 1);
    hipMemsetAsync(C, 0, (size_t)N * 256 * sizeof(float), stream);
    scatter_kernel<256><<<nblk((long)E * 256), BLOCK, 0, stream>>>(B, C, src, dst, nullptr, efet, E);
    relu_kernel<<<nblk((long)N * 256), BLOCK, 0, stream>>>(C, N * 256);   // h1 = C

    // ---- Layer 2: GEMM 256->128 (transform-first), agg, epi, ewa ----
    gemm_kernel<<<nblk((long)N * 128), BLOCK, 0, stream>>>(C, W2, normO, nullptr, nullptr, A, N, 256, 128, 0);
    hipMemsetAsync(B, 0, (size_t)N * 128 * sizeof(float), stream);
    scatter_kernel<128><<<nblk((long)E * 128), BLOCK, 0, stream>>>(A, B, src, dst, nullptr, nullptr, E);
    epi_kernel<<<nblk((long)N * 128), BLOCK, 0, stream>>>(B, normI, b2, B, N, 128, 1);
    hipMemsetAsync(A, 0, (size_t)N * 128 * sizeof(float), stream);
    scatter_kernel<128><<<nblk((long)E * 128), BLOCK, 0, stream>>>(B, A, src, dst, nullptr, efet, E);
    relu_kernel<<<nblk((long)N * 128), BLOCK, 0, stream>>>(A, N * 128);   // h2 = A

    // ---- Layer 3: GEMM 128->64, agg, epi, ewa ----
    gemm_kernel<<<nblk((long)N * 64), BLOCK, 0, stream>>>(A, W3, normO, nullptr, nullptr, B, N, 128, 64, 0);
    hipMemsetAsync(C, 0, (size_t)N * 64 * sizeof(float), stream);
    scatter_kernel<64><<<nblk((long)E * 64), BLOCK, 0, stream>>>(B, C, src, dst, nullptr, nullptr, E);
    epi_kernel<<<nblk((long)N * 64), BLOCK, 0, stream>>>(C, normI, b3, C, N, 64, 1);
    hipMemsetAsync(B, 0, (size_t)N * 64 * sizeof(float), stream);
    scatter_kernel<64><<<nblk((long)E * 64), BLOCK, 0, stream>>>(C, B, src, dst, nullptr, efet, E);
    relu_kernel<<<nblk((long)N * 64), BLOCK, 0, stream>>>(B, N * 64);     // h3 = B

    // ---- Layer 4: GEMM 64->32, agg, epi (no ewa) ----
    gemm_kernel<<<nblk((long)N * 32), BLOCK, 0, stream>>>(B, W4, normO, nullptr, nullptr, A, N, 64, 32, 0);
    hipMemsetAsync(C, 0, (size_t)N * 32 * sizeof(float), stream);
    scatter_kernel<32><<<nblk((long)E * 32), BLOCK, 0, stream>>>(A, C, src, dst, nullptr, nullptr, E);
    epi_kernel<<<nblk((long)N * 32), BLOCK, 0, stream>>>(C, normI, b4, C, N, 32, 1);   // h4 = C

    // ---- Layer 5: GEMM 32->4, agg, epi (no relu) -> d_out ----
    gemm_kernel<<<nblk((long)N * 4), BLOCK, 0, stream>>>(C, W5, normO, nullptr, nullptr, A, N, 32, 4, 0);
    hipMemsetAsync(B, 0, (size_t)N * 4 * sizeof(float), stream);
    scatter_kernel<4><<<nblk((long)E * 4), BLOCK, 0, stream>>>(A, B, src, dst, nullptr, nullptr, E);
    epi_kernel<<<nblk((long)N * 4), BLOCK, 0, stream>>>(B, normI, b5, out, N, 4, 0);
}

// Round 2
// 1608.825 us; speedup vs baseline: 1.9218x; 1.9218x over previous
//
#include <hip/hip_runtime.h>

#define BLOCK 256

// ---------------- degree ----------------
__global__ void deg_kernel(const int* __restrict__ src, const int* __restrict__ dst,
                           float* __restrict__ degO, float* __restrict__ degI, int E) {
    int e = blockIdx.x * blockDim.x + threadIdx.x;
    if (e < E) {
        atomicAdd(&degO[src[e]], 1.0f);
        atomicAdd(&degI[dst[e]], 1.0f);
    }
}

__global__ void norm_kernel(float* __restrict__ d, int n) {
    int i = blockIdx.x * blockDim.x + threadIdx.x;
    if (i < n) d[i] = rsqrtf(fmaxf(d[i], 1.0f));
}

// ---------------- exclusive prefix sum of degI (single block) ----------------
__global__ void scan_kernel(const float* __restrict__ deg, int* __restrict__ rowStart,
                            int N, int E) {
    __shared__ int tmp[1024];
    __shared__ int carry;
    int tid = threadIdx.x;
    if (tid == 0) carry = 0;
    __syncthreads();
    for (int base = 0; base < N; base += 1024) {
        int i = base + tid;
        int v = (i < N) ? (int)deg[i] : 0;
        tmp[tid] = v;
        __syncthreads();
        for (int off = 1; off < 1024; off <<= 1) {
            int t = (tid >= off) ? tmp[tid - off] : 0;
            __syncthreads();
            tmp[tid] += t;
            __syncthreads();
        }
        if (i < N) rowStart[i] = carry + tmp[tid] - v;   // exclusive
        __syncthreads();
        if (tid == 0) carry += tmp[1023];
        __syncthreads();
    }
    if (tid == 0) rowStart[N] = E;
}

__global__ void copy_int_kernel(const int* __restrict__ a, int* __restrict__ b, int n) {
    int i = blockIdx.x * blockDim.x + threadIdx.x;
    if (i < n) b[i] = a[i];
}

// ---------------- permute edges into dst-sorted order ----------------
__global__ void permute_kernel(const int* __restrict__ src, const int* __restrict__ dst,
                               const float* __restrict__ efet, int* __restrict__ cursor,
                               int* __restrict__ srcSorted, float* __restrict__ wSorted, int E) {
    int e = blockIdx.x * blockDim.x + threadIdx.x;
    if (e < E) {
        int d = dst[e];
        int p = atomicAdd(&cursor[d], 1);
        srcSorted[p] = src[e];
        wSorted[p] = efet[e];
    }
}

// ---------------- CSR gather-aggregation, fused epilogue ----------------
// out[v, c] = relu_opt( (sum_{j in row v} in[srcSorted[j], c] * w_j * srcScale[s]) * dstScale[v] + bias[c] )
template <int D>
__global__ void agg_kernel(const float* __restrict__ in, float* __restrict__ out,
                           const int* __restrict__ rowStart, const int* __restrict__ srcSorted,
                           const float* __restrict__ wSorted,    // null -> 1
                           const float* __restrict__ srcScale,   // null -> 1
                           const float* __restrict__ dstScale,   // null -> skip scale+bias
                           const float* __restrict__ bias,
                           int N, int relu) {
    constexpr int TPN = D / 4;   // threads per node, 4 cols each
    int gid = blockIdx.x * blockDim.x + threadIdx.x;
    int v = gid / TPN;
    int c4 = (gid % TPN) * 4;
    if (v >= N) return;
    int beg = rowStart[v], end = rowStart[v + 1];
    float ax = 0.f, ay = 0.f, az = 0.f, aw = 0.f;
    for (int j = beg; j < end; ++j) {
        int s = srcSorted[j];
        const float4 val = *(const float4*)(in + (size_t)s * D + c4);
        float w = 1.0f;
        if (wSorted) w = wSorted[j];
        if (srcScale) w *= srcScale[s];
        ax += val.x * w; ay += val.y * w; az += val.z * w; aw += val.w * w;
    }
    if (dstScale) {
        float sc = dstScale[v];
        ax = ax * sc + bias[c4 + 0];
        ay = ay * sc + bias[c4 + 1];
        az = az * sc + bias[c4 + 2];
        aw = aw * sc + bias[c4 + 3];
    }
    if (relu) {
        ax = fmaxf(ax, 0.f); ay = fmaxf(ay, 0.f);
        az = fmaxf(az, 0.f); aw = fmaxf(aw, 0.f);
    }
    float4 r; r.x = ax; r.y = ay; r.z = az; r.w = aw;
    *(float4*)(out + (size_t)v * D + c4) = r;
}

// ---------------- dense GEMM (one thread per output element) ----------------
__global__ void gemm_kernel(const float* __restrict__ A, const float* __restrict__ W,
                            const float* __restrict__ rowScaleIn,
                            const float* __restrict__ rowScaleOut,
                            const float* __restrict__ bias,
                            float* __restrict__ C, int N, int K1, int K2, int relu) {
    int gid = blockIdx.x * blockDim.x + threadIdx.x;
    int col = gid % K2;
    int row = gid / K2;
    if (row >= N) return;
    const float* a = A + (size_t)row * K1;
    float acc = 0.0f;
    for (int k = 0; k < K1; ++k) acc += a[k] * W[k * K2 + col];
    if (rowScaleIn) acc *= rowScaleIn[row];
    if (rowScaleOut) acc = acc * rowScaleOut[row] + bias[col];
    if (relu) acc = fmaxf(acc, 0.0f);
    C[gid] = acc;
}

static inline int nblk(long n) { return (int)((n + BLOCK - 1) / BLOCK); }

extern "C" void kernel_launch(void* const* d_in, const int* in_sizes, int n_in,
                              void* d_out, int out_size, void* d_ws, size_t ws_size,
                              hipStream_t stream) {
    const float* x    = (const float*)d_in[0];
    const float* efet = (const float*)d_in[1];
    const int*   src  = (const int*)d_in[2];
    const int*   dst  = (const int*)d_in[3];
    const float* W1 = (const float*)d_in[4];  const float* b1 = (const float*)d_in[5];
    const float* W2 = (const float*)d_in[6];  const float* b2 = (const float*)d_in[7];
    const float* W3 = (const float*)d_in[8];  const float* b3 = (const float*)d_in[9];
    const float* W4 = (const float*)d_in[10]; const float* b4 = (const float*)d_in[11];
    const float* W5 = (const float*)d_in[12]; const float* b5 = (const float*)d_in[13];
    float* out = (float*)d_out;

    const int N = in_sizes[0] / 16;
    const int E = in_sizes[2];

    // ---- workspace layout (floats) ----
    float* ws       = (float*)d_ws;
    float* normO    = ws;                                  // N
    float* normI    = ws + (size_t)N;                      // N
    int*   rowStart = (int*)(ws + 2 * (size_t)N);          // N+1 (padded to N+4)
    int*   cursor   = (int*)(ws + 3 * (size_t)N + 4);      // N
    int*   srcSorted= (int*)(ws + 4 * (size_t)N + 4);      // E
    float* wSorted  = ws + 4 * (size_t)N + 4 + (size_t)E;  // E
    float* buf1     = ws + 4 * (size_t)N + 4 + 2 * (size_t)E;   // 256N
    float* buf2     = buf1 + 256 * (size_t)N;                   // 256N

    // ---- degrees + CSR build ----
    hipMemsetAsync(normO, 0, 2 * (size_t)N * sizeof(float), stream);
    deg_kernel<<<nblk(E), BLOCK, 0, stream>>>(src, dst, normO, normI, E);
    scan_kernel<<<1, 1024, 0, stream>>>(normI, rowStart, N, E);
    copy_int_kernel<<<nblk(N), BLOCK, 0, stream>>>(rowStart, cursor, N);
    permute_kernel<<<nblk(E), BLOCK, 0, stream>>>(src, dst, efet, cursor, srcSorted, wSorted, E);
    norm_kernel<<<nblk(2L * N), BLOCK, 0, stream>>>(normO, 2 * N);

    // ---- Layer 1: agg-first in 16-dim (srcScale=normO), GEMM 16->256 (+normI+b1+relu), ewa-agg(+relu) ----
    agg_kernel<16><<<nblk((long)N * 4), BLOCK, 0, stream>>>(
        x, buf1, rowStart, srcSorted, nullptr, normO, nullptr, nullptr, N, 0);
    gemm_kernel<<<nblk((long)N * 256), BLOCK, 0, stream>>>(
        buf1, W1, nullptr, normI, b1, buf2, N, 16, 256, 1);
    agg_kernel<256><<<nblk((long)N * 64), BLOCK, 0, stream>>>(
        buf2, buf1, rowStart, srcSorted, wSorted, nullptr, nullptr, nullptr, N, 1);   // h1 = buf1

    // ---- Layer 2: GEMM 256->128 (rowScaleIn=normO), gc-agg(+normI+b2+relu), ewa-agg(+relu) ----
    gemm_kernel<<<nblk((long)N * 128), BLOCK, 0, stream>>>(
        buf1, W2, normO, nullptr, nullptr, buf2, N, 256, 128, 0);
    agg_kernel<128><<<nblk((long)N * 32), BLOCK, 0, stream>>>(
        buf2, buf2 + 128 * (size_t)N, rowStart, srcSorted, nullptr, nullptr, normI, b2, N, 1);
    agg_kernel<128><<<nblk((long)N * 32), BLOCK, 0, stream>>>(
        buf2 + 128 * (size_t)N, buf1, rowStart, srcSorted, wSorted, nullptr, nullptr, nullptr, N, 1); // h2 = buf1[0:128N]

    // ---- Layer 3: GEMM 128->64, gc-agg, ewa-agg ----
    gemm_kernel<<<nblk((long)N * 64), BLOCK, 0, stream>>>(
        buf1, W3, normO, nullptr, nullptr, buf1 + 128 * (size_t)N, N, 128, 64, 0);
    agg_kernel<64><<<nblk((long)N * 16), BLOCK, 0, stream>>>(
        buf1 + 128 * (size_t)N, buf1 + 192 * (size_t)N, rowStart, srcSorted, nullptr, nullptr, normI, b3, N, 1);
    agg_kernel<64><<<nblk((long)N * 16), BLOCK, 0, stream>>>(
        buf1 + 192 * (size_t)N, buf2, rowStart, srcSorted, wSorted, nullptr, nullptr, nullptr, N, 1); // h3 = buf2[0:64N]

    // ---- Layer 4: GEMM 64->32, gc-agg (+relu), no ewa ----
    gemm_kernel<<<nblk((long)N * 32), BLOCK, 0, stream>>>(
        buf2, W4, normO, nullptr, nullptr, buf2 + 64 * (size_t)N, N, 64, 32, 0);
    agg_kernel<32><<<nblk((long)N * 8), BLOCK, 0, stream>>>(
        buf2 + 64 * (size_t)N, buf1, rowStart, srcSorted, nullptr, nullptr, normI, b4, N, 1);          // h4 = buf1[0:32N]

    // ---- Layer 5: GEMM 32->4, gc-agg (no relu) -> out ----
    gemm_kernel<<<nblk((long)N * 4), BLOCK, 0, stream>>>(
        buf1, W5, normO, nullptr, nullptr, buf1 + 32 * (size_t)N, N, 32, 4, 0);
    agg_kernel<4><<<nblk((long)N * 1), BLOCK, 0, stream>>>(
        buf1 + 32 * (size_t)N, out, rowStart, srcSorted, nullptr, nullptr, normI, b5, N, 0);
}

// Round 3
// 836.990 us; speedup vs baseline: 3.6940x; 1.9222x over previous
//
#include <hip/hip_runtime.h>

#define BLOCK 256

// ---------------- degree ----------------
__global__ void deg_kernel(const int* __restrict__ src, const int* __restrict__ dst,
                           float* __restrict__ degO, float* __restrict__ degI, int E) {
    int e = blockIdx.x * blockDim.x + threadIdx.x;
    if (e < E) {
        atomicAdd(&degO[src[e]], 1.0f);
        atomicAdd(&degI[dst[e]], 1.0f);
    }
}

__global__ void norm_kernel(float* __restrict__ d, int n) {
    int i = blockIdx.x * blockDim.x + threadIdx.x;
    if (i < n) d[i] = rsqrtf(fmaxf(d[i], 1.0f));
}

// ---------------- exclusive prefix sum of degI (single block) ----------------
__global__ void scan_kernel(const float* __restrict__ deg, int* __restrict__ rowStart,
                            int N, int E) {
    __shared__ int tmp[1024];
    __shared__ int carry;
    int tid = threadIdx.x;
    if (tid == 0) carry = 0;
    __syncthreads();
    for (int base = 0; base < N; base += 1024) {
        int i = base + tid;
        int v = (i < N) ? (int)deg[i] : 0;
        tmp[tid] = v;
        __syncthreads();
        for (int off = 1; off < 1024; off <<= 1) {
            int t = (tid >= off) ? tmp[tid - off] : 0;
            __syncthreads();
            tmp[tid] += t;
            __syncthreads();
        }
        if (i < N) rowStart[i] = carry + tmp[tid] - v;   // exclusive
        __syncthreads();
        if (tid == 0) carry += tmp[1023];
        __syncthreads();
    }
    if (tid == 0) rowStart[N] = E;
}

__global__ void copy_int_kernel(const int* __restrict__ a, int* __restrict__ b, int n) {
    int i = blockIdx.x * blockDim.x + threadIdx.x;
    if (i < n) b[i] = a[i];
}

// ---------------- permute edges into dst-sorted order ----------------
__global__ void permute_kernel(const int* __restrict__ src, const int* __restrict__ dst,
                               const float* __restrict__ efet, int* __restrict__ cursor,
                               int* __restrict__ srcSorted, float* __restrict__ wSorted, int E) {
    int e = blockIdx.x * blockDim.x + threadIdx.x;
    if (e < E) {
        int d = dst[e];
        int p = atomicAdd(&cursor[d], 1);
        srcSorted[p] = src[e];
        wSorted[p] = efet[e];
    }
}

// ---------------- CSR gather-aggregation, fused epilogue ----------------
template <int D>
__global__ void agg_kernel(const float* __restrict__ in, float* __restrict__ out,
                           const int* __restrict__ rowStart, const int* __restrict__ srcSorted,
                           const float* __restrict__ wSorted,    // null -> 1
                           const float* __restrict__ srcScale,   // null -> 1
                           const float* __restrict__ dstScale,   // null -> skip scale+bias
                           const float* __restrict__ bias,
                           int N, int relu) {
    constexpr int TPN = D / 4;   // threads per node, 4 cols each
    int gid = blockIdx.x * blockDim.x + threadIdx.x;
    int v = gid / TPN;
    int c4 = (gid % TPN) * 4;
    if (v >= N) return;
    int beg = rowStart[v], end = rowStart[v + 1];
    float ax = 0.f, ay = 0.f, az = 0.f, aw = 0.f;
    for (int j = beg; j < end; ++j) {
        int s = srcSorted[j];
        const float4 val = *(const float4*)(in + (size_t)s * D + c4);
        float w = 1.0f;
        if (wSorted) w = wSorted[j];
        if (srcScale) w *= srcScale[s];
        ax += val.x * w; ay += val.y * w; az += val.z * w; aw += val.w * w;
    }
    if (dstScale) {
        float sc = dstScale[v];
        ax = ax * sc + bias[c4 + 0];
        ay = ay * sc + bias[c4 + 1];
        az = az * sc + bias[c4 + 2];
        aw = aw * sc + bias[c4 + 3];
    }
    if (relu) {
        ax = fmaxf(ax, 0.f); ay = fmaxf(ay, 0.f);
        az = fmaxf(az, 0.f); aw = fmaxf(aw, 0.f);
    }
    float4 r; r.x = ax; r.y = ay; r.z = az; r.w = aw;
    *(float4*)(out + (size_t)v * D + c4) = r;
}

// ---------------- tiled register-blocked GEMM ----------------
// C[N,TN] = A[N,K1] @ W[K1,TN]  (TN == K2 of the layer)
// rowScaleIn scales A rows (applied at load). rowScaleOut+bias+relu on store.
template <int KT, int RPT, int TN>
__global__ __launch_bounds__(256) void gemm_tiled(
    const float* __restrict__ A, const float* __restrict__ W,
    const float* __restrict__ rowScaleIn,   // null -> 1
    const float* __restrict__ rowScaleOut,  // null -> no scale/bias
    const float* __restrict__ bias,
    float* __restrict__ C, int N, int K1, int relu)
{
    constexpr int NC8 = TN / 8;          // col groups of 8
    constexpr int RT  = 256 / NC8;       // row-threads
    constexpr int TM  = RT * RPT;        // tile rows
    constexpr int AFPT = TM * KT / 256;  // A floats per thread (stage)
    constexpr int WF4  = KT * TN / 1024; // W float4s per thread (stage)

    __shared__ float Alds[KT][TM];
    __shared__ float Wlds[KT][TN];

    const int t    = threadIdx.x;
    const int cg   = t % NC8;
    const int rt   = t / NC8;
    const int c0   = cg * 8;
    const int row0 = blockIdx.x * TM;

    // A staging coords: row = t % TM, k-chunk of AFPT
    const int arow   = t % TM;
    const int akb    = (t / TM) * AFPT;
    const int arow_g = row0 + arow;
    float rsc = 1.0f;
    if (rowScaleIn && arow_g < N) rsc = rowScaleIn[arow_g];

    float acc[RPT][8];
#pragma unroll
    for (int r = 0; r < RPT; ++r)
#pragma unroll
        for (int j = 0; j < 8; ++j) acc[r][j] = 0.f;

    for (int k0 = 0; k0 < K1; k0 += KT) {
        // ---- stage A tile, transposed + scaled ----
        float av[AFPT];
        if (arow_g < N) {
            const float* ag = A + (size_t)arow_g * K1 + k0 + akb;
            if constexpr (AFPT % 4 == 0) {
#pragma unroll
                for (int j4 = 0; j4 < AFPT; j4 += 4)
                    *(float4*)&av[j4] = *(const float4*)(ag + j4);
            } else {
                *(float2*)&av[0] = *(const float2*)ag;
            }
        } else {
#pragma unroll
            for (int j = 0; j < AFPT; ++j) av[j] = 0.f;
        }
#pragma unroll
        for (int j = 0; j < AFPT; ++j)
            Alds[akb + j][arow] = av[j] * rsc;

        // ---- stage W tile (straight copy, coalesced) ----
        {
            const float4* wg = (const float4*)(W + (size_t)k0 * TN);
            float4* wl = (float4*)&Wlds[0][0];
#pragma unroll
            for (int j = 0; j < WF4; ++j) wl[j * 256 + t] = wg[j * 256 + t];
        }
        __syncthreads();

#pragma unroll
        for (int kk = 0; kk < KT; ++kk) {
            float a[RPT];
            if constexpr (RPT == 4) {
                float4 avv = *(const float4*)&Alds[kk][rt * 4];
                a[0] = avv.x; a[1] = avv.y; a[2] = avv.z; a[3] = avv.w;
            } else if constexpr (RPT == 2) {
                float2 avv = *(const float2*)&Alds[kk][rt * 2];
                a[0] = avv.x; a[1] = avv.y;
            } else {
                a[0] = Alds[kk][rt];
            }
            float4 w0 = *(const float4*)&Wlds[kk][c0];
            float4 w1 = *(const float4*)&Wlds[kk][c0 + 4];
#pragma unroll
            for (int r = 0; r < RPT; ++r) {
                acc[r][0] += a[r] * w0.x; acc[r][1] += a[r] * w0.y;
                acc[r][2] += a[r] * w0.z; acc[r][3] += a[r] * w0.w;
                acc[r][4] += a[r] * w1.x; acc[r][5] += a[r] * w1.y;
                acc[r][6] += a[r] * w1.z; acc[r][7] += a[r] * w1.w;
            }
        }
        __syncthreads();
    }

    // ---- epilogue ----
#pragma unroll
    for (int r = 0; r < RPT; ++r) {
        int row_g = row0 + rt * RPT + r;
        if (row_g >= N) continue;
        float f[8];
        if (rowScaleOut) {
            float sc = rowScaleOut[row_g];
#pragma unroll
            for (int j = 0; j < 8; ++j) f[j] = acc[r][j] * sc + bias[c0 + j];
        } else {
#pragma unroll
            for (int j = 0; j < 8; ++j) f[j] = acc[r][j];
        }
        if (relu) {
#pragma unroll
            for (int j = 0; j < 8; ++j) f[j] = fmaxf(f[j], 0.f);
        }
        float* cp = C + (size_t)row_g * TN + c0;
        *(float4*)cp       = make_float4(f[0], f[1], f[2], f[3]);
        *(float4*)(cp + 4) = make_float4(f[4], f[5], f[6], f[7]);
    }
}

// ---------------- naive GEMM (kept for K2=4 layer) ----------------
__global__ void gemm_kernel(const float* __restrict__ A, const float* __restrict__ W,
                            const float* __restrict__ rowScaleIn,
                            const float* __restrict__ rowScaleOut,
                            const float* __restrict__ bias,
                            float* __restrict__ C, int N, int K1, int K2, int relu) {
    int gid = blockIdx.x * blockDim.x + threadIdx.x;
    int col = gid % K2;
    int row = gid / K2;
    if (row >= N) return;
    const float* a = A + (size_t)row * K1;
    float acc = 0.0f;
    for (int k = 0; k < K1; ++k) acc += a[k] * W[k * K2 + col];
    if (rowScaleIn) acc *= rowScaleIn[row];
    if (rowScaleOut) acc = acc * rowScaleOut[row] + bias[col];
    if (relu) acc = fmaxf(acc, 0.0f);
    C[gid] = acc;
}

static inline int nblk(long n) { return (int)((n + BLOCK - 1) / BLOCK); }

extern "C" void kernel_launch(void* const* d_in, const int* in_sizes, int n_in,
                              void* d_out, int out_size, void* d_ws, size_t ws_size,
                              hipStream_t stream) {
    const float* x    = (const float*)d_in[0];
    const float* efet = (const float*)d_in[1];
    const int*   src  = (const int*)d_in[2];
    const int*   dst  = (const int*)d_in[3];
    const float* W1 = (const float*)d_in[4];  const float* b1 = (const float*)d_in[5];
    const float* W2 = (const float*)d_in[6];  const float* b2 = (const float*)d_in[7];
    const float* W3 = (const float*)d_in[8];  const float* b3 = (const float*)d_in[9];
    const float* W4 = (const float*)d_in[10]; const float* b4 = (const float*)d_in[11];
    const float* W5 = (const float*)d_in[12]; const float* b5 = (const float*)d_in[13];
    float* out = (float*)d_out;

    const int N = in_sizes[0] / 16;
    const int E = in_sizes[2];

    // ---- workspace layout (floats) ----
    float* ws       = (float*)d_ws;
    float* normO    = ws;                                  // N
    float* normI    = ws + (size_t)N;                      // N
    int*   rowStart = (int*)(ws + 2 * (size_t)N);          // N+1 (padded to N+4)
    int*   cursor   = (int*)(ws + 3 * (size_t)N + 4);      // N
    int*   srcSorted= (int*)(ws + 4 * (size_t)N + 4);      // E
    float* wSorted  = ws + 4 * (size_t)N + 4 + (size_t)E;  // E
    float* buf1     = ws + 4 * (size_t)N + 4 + 2 * (size_t)E;   // 256N
    float* buf2     = buf1 + 256 * (size_t)N;                   // 256N

    // ---- degrees + CSR build ----
    hipMemsetAsync(normO, 0, 2 * (size_t)N * sizeof(float), stream);
    deg_kernel<<<nblk(E), BLOCK, 0, stream>>>(src, dst, normO, normI, E);
    scan_kernel<<<1, 1024, 0, stream>>>(normI, rowStart, N, E);
    copy_int_kernel<<<nblk(N), BLOCK, 0, stream>>>(rowStart, cursor, N);
    permute_kernel<<<nblk(E), BLOCK, 0, stream>>>(src, dst, efet, cursor, srcSorted, wSorted, E);
    norm_kernel<<<nblk(2L * N), BLOCK, 0, stream>>>(normO, 2 * N);

    // ---- Layer 1: agg-first in 16-dim (srcScale=normO), GEMM 16->256 (+normI+b1+relu), ewa-agg(+relu) ----
    agg_kernel<16><<<nblk((long)N * 4), BLOCK, 0, stream>>>(
        x, buf1, rowStart, srcSorted, nullptr, normO, nullptr, nullptr, N, 0);
    gemm_tiled<16, 4, 256><<<(N + 31) / 32, 256, 0, stream>>>(
        buf1, W1, nullptr, normI, b1, buf2, N, 16, 1);
    agg_kernel<256><<<nblk((long)N * 64), BLOCK, 0, stream>>>(
        buf2, buf1, rowStart, srcSorted, wSorted, nullptr, nullptr, nullptr, N, 1);   // h1 = buf1

    // ---- Layer 2: GEMM 256->128 (rowScaleIn=normO), gc-agg(+normI+b2+relu), ewa-agg(+relu) ----
    gemm_tiled<32, 4, 128><<<(N + 63) / 64, 256, 0, stream>>>(
        buf1, W2, normO, nullptr, nullptr, buf2, N, 256, 0);
    agg_kernel<128><<<nblk((long)N * 32), BLOCK, 0, stream>>>(
        buf2, buf2 + 128 * (size_t)N, rowStart, srcSorted, nullptr, nullptr, normI, b2, N, 1);
    agg_kernel<128><<<nblk((long)N * 32), BLOCK, 0, stream>>>(
        buf2 + 128 * (size_t)N, buf1, rowStart, srcSorted, wSorted, nullptr, nullptr, nullptr, N, 1); // h2 = buf1[0:128N]

    // ---- Layer 3: GEMM 128->64, gc-agg, ewa-agg ----
    gemm_tiled<32, 2, 64><<<(N + 63) / 64, 256, 0, stream>>>(
        buf1, W3, normO, nullptr, nullptr, buf1 + 128 * (size_t)N, N, 128, 0);
    agg_kernel<64><<<nblk((long)N * 16), BLOCK, 0, stream>>>(
        buf1 + 128 * (size_t)N, buf1 + 192 * (size_t)N, rowStart, srcSorted, nullptr, nullptr, normI, b3, N, 1);
    agg_kernel<64><<<nblk((long)N * 16), BLOCK, 0, stream>>>(
        buf1 + 192 * (size_t)N, buf2, rowStart, srcSorted, wSorted, nullptr, nullptr, nullptr, N, 1); // h3 = buf2[0:64N]

    // ---- Layer 4: GEMM 64->32, gc-agg (+relu), no ewa ----
    gemm_tiled<32, 1, 32><<<(N + 63) / 64, 256, 0, stream>>>(
        buf2, W4, normO, nullptr, nullptr, buf2 + 64 * (size_t)N, N, 64, 0);
    agg_kernel<32><<<nblk((long)N * 8), BLOCK, 0, stream>>>(
        buf2 + 64 * (size_t)N, buf1, rowStart, srcSorted, nullptr, nullptr, normI, b4, N, 1);          // h4 = buf1[0:32N]

    // ---- Layer 5: GEMM 32->4, gc-agg (no relu) -> out ----
    gemm_kernel<<<nblk((long)N * 4), BLOCK, 0, stream>>>(
        buf1, W5, normO, nullptr, nullptr, buf1 + 32 * (size_t)N, N, 32, 4, 0);
    agg_kernel<4><<<nblk((long)N * 1), BLOCK, 0, stream>>>(
        buf1 + 32 * (size_t)N, out, rowStart, srcSorted, nullptr, nullptr, normI, b5, N, 0);
}

// Round 4
// 723.201 us; speedup vs baseline: 4.2752x; 1.1573x over previous
//
#include <hip/hip_runtime.h>

#define BLOCK 256

// ---------------- degree ----------------
__global__ void deg_kernel(const int* __restrict__ src, const int* __restrict__ dst,
                           float* __restrict__ degO, float* __restrict__ degI, int E) {
    int e = blockIdx.x * blockDim.x + threadIdx.x;
    if (e < E) {
        atomicAdd(&degO[src[e]], 1.0f);
        atomicAdd(&degI[dst[e]], 1.0f);
    }
}

__global__ void norm_kernel(float* __restrict__ d, int n) {
    int i = blockIdx.x * blockDim.x + threadIdx.x;
    if (i < n) d[i] = rsqrtf(fmaxf(d[i], 1.0f));
}

// ---------------- hierarchical exclusive scan of degI ----------------
__global__ void scan_local(const float* __restrict__ deg, int* __restrict__ rowStart,
                           int* __restrict__ blockSums, int N) {
    __shared__ int tmp[1024];
    int tid = threadIdx.x;
    int i = blockIdx.x * 1024 + tid;
    int v = (i < N) ? (int)deg[i] : 0;
    tmp[tid] = v;
    __syncthreads();
    for (int off = 1; off < 1024; off <<= 1) {
        int t = (tid >= off) ? tmp[tid - off] : 0;
        __syncthreads();
        tmp[tid] += t;
        __syncthreads();
    }
    if (i < N) rowStart[i] = tmp[tid] - v;           // exclusive within block
    if (tid == 0) blockSums[blockIdx.x] = tmp[1023]; // block total
}

__global__ void scan_sums(int* __restrict__ blockSums, int nb) {
    __shared__ int tmp[64];
    int tid = threadIdx.x;
    int v = (tid < nb) ? blockSums[tid] : 0;
    tmp[tid] = v;
    __syncthreads();
    for (int off = 1; off < 64; off <<= 1) {
        int t = (tid >= off) ? tmp[tid - off] : 0;
        __syncthreads();
        tmp[tid] += t;
        __syncthreads();
    }
    if (tid < nb) blockSums[tid] = tmp[tid] - v;     // exclusive
}

__global__ void scan_add(int* __restrict__ rowStart, const int* __restrict__ blockSums,
                         int N, int E) {
    int i = blockIdx.x * blockDim.x + threadIdx.x;
    if (i < N) rowStart[i] += blockSums[i >> 10];
    if (i == N) rowStart[N] = E;
}

__global__ void copy_int_kernel(const int* __restrict__ a, int* __restrict__ b, int n) {
    int i = blockIdx.x * blockDim.x + threadIdx.x;
    if (i < n) b[i] = a[i];
}

// ---------------- permute edges into dst-sorted order ----------------
__global__ void permute_kernel(const int* __restrict__ src, const int* __restrict__ dst,
                               const float* __restrict__ efet, int* __restrict__ cursor,
                               int* __restrict__ srcSorted, float* __restrict__ wSorted, int E) {
    int e = blockIdx.x * blockDim.x + threadIdx.x;
    if (e < E) {
        int d = dst[e];
        int p = atomicAdd(&cursor[d], 1);
        srcSorted[p] = src[e];
        wSorted[p] = efet[e];
    }
}

// ---------------- CSR gather-aggregation, fused epilogue, 4x unrolled ----------------
template <int D>
__global__ void agg_kernel(const float* __restrict__ in, float* __restrict__ out,
                           const int* __restrict__ rowStart, const int* __restrict__ srcSorted,
                           const float* __restrict__ wSorted,    // null -> 1
                           const float* __restrict__ srcScale,   // null -> 1
                           const float* __restrict__ dstScale,   // null -> skip scale+bias
                           const float* __restrict__ bias,
                           int N, int relu) {
    constexpr int TPN = D / 4;   // threads per node, 4 cols each
    int gid = blockIdx.x * blockDim.x + threadIdx.x;
    int v = gid / TPN;
    int c4 = (gid % TPN) * 4;
    if (v >= N) return;
    int beg = rowStart[v], end = rowStart[v + 1];
    float ax = 0.f, ay = 0.f, az = 0.f, aw = 0.f;
    const float* base = in + c4;

    int j = beg;
    for (; j + 4 <= end; j += 4) {
        int s0 = srcSorted[j + 0], s1 = srcSorted[j + 1];
        int s2 = srcSorted[j + 2], s3 = srcSorted[j + 3];
        float w0 = 1.f, w1 = 1.f, w2 = 1.f, w3 = 1.f;
        if (wSorted) {
            w0 = wSorted[j + 0]; w1 = wSorted[j + 1];
            w2 = wSorted[j + 2]; w3 = wSorted[j + 3];
        }
        if (srcScale) {
            w0 *= srcScale[s0]; w1 *= srcScale[s1];
            w2 *= srcScale[s2]; w3 *= srcScale[s3];
        }
        // 4 independent gathers in flight
        float4 x0 = *(const float4*)(base + (size_t)s0 * D);
        float4 x1 = *(const float4*)(base + (size_t)s1 * D);
        float4 x2 = *(const float4*)(base + (size_t)s2 * D);
        float4 x3 = *(const float4*)(base + (size_t)s3 * D);
        ax += x0.x * w0; ay += x0.y * w0; az += x0.z * w0; aw += x0.w * w0;
        ax += x1.x * w1; ay += x1.y * w1; az += x1.z * w1; aw += x1.w * w1;
        ax += x2.x * w2; ay += x2.y * w2; az += x2.z * w2; aw += x2.w * w2;
        ax += x3.x * w3; ay += x3.y * w3; az += x3.z * w3; aw += x3.w * w3;
    }
    for (; j < end; ++j) {
        int s = srcSorted[j];
        float w = 1.0f;
        if (wSorted) w = wSorted[j];
        if (srcScale) w *= srcScale[s];
        float4 val = *(const float4*)(base + (size_t)s * D);
        ax += val.x * w; ay += val.y * w; az += val.z * w; aw += val.w * w;
    }
    if (dstScale) {
        float sc = dstScale[v];
        ax = ax * sc + bias[c4 + 0];
        ay = ay * sc + bias[c4 + 1];
        az = az * sc + bias[c4 + 2];
        aw = aw * sc + bias[c4 + 3];
    }
    if (relu) {
        ax = fmaxf(ax, 0.f); ay = fmaxf(ay, 0.f);
        az = fmaxf(az, 0.f); aw = fmaxf(aw, 0.f);
    }
    float4 r; r.x = ax; r.y = ay; r.z = az; r.w = aw;
    *(float4*)(out + (size_t)v * D + c4) = r;
}

// ---------------- tiled register-blocked GEMM ----------------
template <int KT, int RPT, int TN>
__global__ __launch_bounds__(256) void gemm_tiled(
    const float* __restrict__ A, const float* __restrict__ W,
    const float* __restrict__ rowScaleIn,   // null -> 1
    const float* __restrict__ rowScaleOut,  // null -> no scale/bias
    const float* __restrict__ bias,
    float* __restrict__ C, int N, int K1, int relu)
{
    constexpr int NC8 = TN / 8;          // col groups of 8
    constexpr int RT  = 256 / NC8;       // row-threads
    constexpr int TM  = RT * RPT;        // tile rows
    constexpr int AFPT = TM * KT / 256;  // A floats per thread (stage)
    constexpr int WF4  = KT * TN / 1024; // W float4s per thread (stage)

    __shared__ float Alds[KT][TM];
    __shared__ float Wlds[KT][TN];

    const int t    = threadIdx.x;
    const int cg   = t % NC8;
    const int rt   = t / NC8;
    const int c0   = cg * 8;
    const int row0 = blockIdx.x * TM;

    const int arow   = t % TM;
    const int akb    = (t / TM) * AFPT;
    const int arow_g = row0 + arow;
    float rsc = 1.0f;
    if (rowScaleIn && arow_g < N) rsc = rowScaleIn[arow_g];

    float acc[RPT][8];
#pragma unroll
    for (int r = 0; r < RPT; ++r)
#pragma unroll
        for (int j = 0; j < 8; ++j) acc[r][j] = 0.f;

    for (int k0 = 0; k0 < K1; k0 += KT) {
        float av[AFPT];
        if (arow_g < N) {
            const float* ag = A + (size_t)arow_g * K1 + k0 + akb;
            if constexpr (AFPT % 4 == 0) {
#pragma unroll
                for (int j4 = 0; j4 < AFPT; j4 += 4)
                    *(float4*)&av[j4] = *(const float4*)(ag + j4);
            } else {
                *(float2*)&av[0] = *(const float2*)ag;
            }
        } else {
#pragma unroll
            for (int j = 0; j < AFPT; ++j) av[j] = 0.f;
        }
#pragma unroll
        for (int j = 0; j < AFPT; ++j)
            Alds[akb + j][arow] = av[j] * rsc;

        {
            const float4* wg = (const float4*)(W + (size_t)k0 * TN);
            float4* wl = (float4*)&Wlds[0][0];
#pragma unroll
            for (int j = 0; j < WF4; ++j) wl[j * 256 + t] = wg[j * 256 + t];
        }
        __syncthreads();

#pragma unroll
        for (int kk = 0; kk < KT; ++kk) {
            float a[RPT];
            if constexpr (RPT == 4) {
                float4 avv = *(const float4*)&Alds[kk][rt * 4];
                a[0] = avv.x; a[1] = avv.y; a[2] = avv.z; a[3] = avv.w;
            } else if constexpr (RPT == 2) {
                float2 avv = *(const float2*)&Alds[kk][rt * 2];
                a[0] = avv.x; a[1] = avv.y;
            } else {
                a[0] = Alds[kk][rt];
            }
            float4 w0 = *(const float4*)&Wlds[kk][c0];
            float4 w1 = *(const float4*)&Wlds[kk][c0 + 4];
#pragma unroll
            for (int r = 0; r < RPT; ++r) {
                acc[r][0] += a[r] * w0.x; acc[r][1] += a[r] * w0.y;
                acc[r][2] += a[r] * w0.z; acc[r][3] += a[r] * w0.w;
                acc[r][4] += a[r] * w1.x; acc[r][5] += a[r] * w1.y;
                acc[r][6] += a[r] * w1.z; acc[r][7] += a[r] * w1.w;
            }
        }
        __syncthreads();
    }

#pragma unroll
    for (int r = 0; r < RPT; ++r) {
        int row_g = row0 + rt * RPT + r;
        if (row_g >= N) continue;
        float f[8];
        if (rowScaleOut) {
            float sc = rowScaleOut[row_g];
#pragma unroll
            for (int j = 0; j < 8; ++j) f[j] = acc[r][j] * sc + bias[c0 + j];
        } else {
#pragma unroll
            for (int j = 0; j < 8; ++j) f[j] = acc[r][j];
        }
        if (relu) {
#pragma unroll
            for (int j = 0; j < 8; ++j) f[j] = fmaxf(f[j], 0.f);
        }
        float* cp = C + (size_t)row_g * TN + c0;
        *(float4*)cp       = make_float4(f[0], f[1], f[2], f[3]);
        *(float4*)(cp + 4) = make_float4(f[4], f[5], f[6], f[7]);
    }
}

// ---------------- naive GEMM (kept for K2=4 layer) ----------------
__global__ void gemm_kernel(const float* __restrict__ A, const float* __restrict__ W,
                            const float* __restrict__ rowScaleIn,
                            const float* __restrict__ rowScaleOut,
                            const float* __restrict__ bias,
                            float* __restrict__ C, int N, int K1, int K2, int relu) {
    int gid = blockIdx.x * blockDim.x + threadIdx.x;
    int col = gid % K2;
    int row = gid / K2;
    if (row >= N) return;
    const float* a = A + (size_t)row * K1;
    float acc = 0.0f;
    for (int k = 0; k < K1; ++k) acc += a[k] * W[k * K2 + col];
    if (rowScaleIn) acc *= rowScaleIn[row];
    if (rowScaleOut) acc = acc * rowScaleOut[row] + bias[col];
    if (relu) acc = fmaxf(acc, 0.0f);
    C[gid] = acc;
}

static inline int nblk(long n) { return (int)((n + BLOCK - 1) / BLOCK); }

extern "C" void kernel_launch(void* const* d_in, const int* in_sizes, int n_in,
                              void* d_out, int out_size, void* d_ws, size_t ws_size,
                              hipStream_t stream) {
    const float* x    = (const float*)d_in[0];
    const float* efet = (const float*)d_in[1];
    const int*   src  = (const int*)d_in[2];
    const int*   dst  = (const int*)d_in[3];
    const float* W1 = (const float*)d_in[4];  const float* b1 = (const float*)d_in[5];
    const float* W2 = (const float*)d_in[6];  const float* b2 = (const float*)d_in[7];
    const float* W3 = (const float*)d_in[8];  const float* b3 = (const float*)d_in[9];
    const float* W4 = (const float*)d_in[10]; const float* b4 = (const float*)d_in[11];
    const float* W5 = (const float*)d_in[12]; const float* b5 = (const float*)d_in[13];
    float* out = (float*)d_out;

    const int N = in_sizes[0] / 16;
    const int E = in_sizes[2];
    const int NB1024 = (N + 1023) / 1024;

    // ---- workspace layout (floats) ----
    float* ws       = (float*)d_ws;
    float* normO    = ws;                                  // N
    float* normI    = ws + (size_t)N;                      // N (holds degI pre-norm)
    int*   rowStart = (int*)(ws + 2 * (size_t)N);          // N+1 (pad 4)
    int*   cursor   = (int*)(ws + 3 * (size_t)N + 4);      // N
    int*   blockSums= (int*)(ws + 4 * (size_t)N + 4);      // 64
    int*   srcSorted= (int*)(ws + 4 * (size_t)N + 68);     // E
    float* wSorted  = ws + 4 * (size_t)N + 68 + (size_t)E; // E
    float* buf1     = ws + 4 * (size_t)N + 68 + 2 * (size_t)E;  // 256N
    float* buf2     = buf1 + 256 * (size_t)N;                   // 256N

    // ---- degrees + CSR build ----
    hipMemsetAsync(normO, 0, 2 * (size_t)N * sizeof(float), stream);
    deg_kernel<<<nblk(E), BLOCK, 0, stream>>>(src, dst, normO, normI, E);
    scan_local<<<NB1024, 1024, 0, stream>>>(normI, rowStart, blockSums, N);
    scan_sums<<<1, 64, 0, stream>>>(blockSums, NB1024);
    scan_add<<<nblk(N + 1), BLOCK, 0, stream>>>(rowStart, blockSums, N, E);
    copy_int_kernel<<<nblk(N), BLOCK, 0, stream>>>(rowStart, cursor, N);
    permute_kernel<<<nblk(E), BLOCK, 0, stream>>>(src, dst, efet, cursor, srcSorted, wSorted, E);
    norm_kernel<<<nblk(2L * N), BLOCK, 0, stream>>>(normO, 2 * N);

    // ---- Layer 1: agg-first in 16-dim (srcScale=normO), GEMM 16->256 (+normI+b1+relu), ewa-agg(+relu) ----
    agg_kernel<16><<<nblk((long)N * 4), BLOCK, 0, stream>>>(
        x, buf1, rowStart, srcSorted, nullptr, normO, nullptr, nullptr, N, 0);
    gemm_tiled<16, 4, 256><<<(N + 31) / 32, 256, 0, stream>>>(
        buf1, W1, nullptr, normI, b1, buf2, N, 16, 1);
    agg_kernel<256><<<nblk((long)N * 64), BLOCK, 0, stream>>>(
        buf2, buf1, rowStart, srcSorted, wSorted, nullptr, nullptr, nullptr, N, 1);   // h1 = buf1

    // ---- Layer 2: GEMM 256->128 (rowScaleIn=normO), gc-agg(+normI+b2+relu), ewa-agg(+relu) ----
    gemm_tiled<32, 4, 128><<<(N + 63) / 64, 256, 0, stream>>>(
        buf1, W2, normO, nullptr, nullptr, buf2, N, 256, 0);
    agg_kernel<128><<<nblk((long)N * 32), BLOCK, 0, stream>>>(
        buf2, buf2 + 128 * (size_t)N, rowStart, srcSorted, nullptr, nullptr, normI, b2, N, 1);
    agg_kernel<128><<<nblk((long)N * 32), BLOCK, 0, stream>>>(
        buf2 + 128 * (size_t)N, buf1, rowStart, srcSorted, wSorted, nullptr, nullptr, nullptr, N, 1); // h2 = buf1[0:128N]

    // ---- Layer 3: GEMM 128->64, gc-agg, ewa-agg ----
    gemm_tiled<32, 2, 64><<<(N + 63) / 64, 256, 0, stream>>>(
        buf1, W3, normO, nullptr, nullptr, buf1 + 128 * (size_t)N, N, 128, 0);
    agg_kernel<64><<<nblk((long)N * 16), BLOCK, 0, stream>>>(
        buf1 + 128 * (size_t)N, buf1 + 192 * (size_t)N, rowStart, srcSorted, nullptr, nullptr, normI, b3, N, 1);
    agg_kernel<64><<<nblk((long)N * 16), BLOCK, 0, stream>>>(
        buf1 + 192 * (size_t)N, buf2, rowStart, srcSorted, wSorted, nullptr, nullptr, nullptr, N, 1); // h3 = buf2[0:64N]

    // ---- Layer 4: GEMM 64->32, gc-agg (+relu), no ewa ----
    gemm_tiled<32, 1, 32><<<(N + 63) / 64, 256, 0, stream>>>(
        buf2, W4, normO, nullptr, nullptr, buf2 + 64 * (size_t)N, N, 64, 0);
    agg_kernel<32><<<nblk((long)N * 8), BLOCK, 0, stream>>>(
        buf2 + 64 * (size_t)N, buf1, rowStart, srcSorted, nullptr, nullptr, normI, b4, N, 1);          // h4 = buf1[0:32N]

    // ---- Layer 5: GEMM 32->4, gc-agg (no relu) -> out ----
    gemm_kernel<<<nblk((long)N * 4), BLOCK, 0, stream>>>(
        buf1, W5, normO, nullptr, nullptr, buf1 + 32 * (size_t)N, N, 32, 4, 0);
    agg_kernel<4><<<nblk((long)N * 1), BLOCK, 0, stream>>>(
        buf1 + 32 * (size_t)N, out, rowStart, srcSorted, nullptr, nullptr, normI, b5, N, 0);
}

// Round 5
// 565.712 us; speedup vs baseline: 5.4654x; 1.2784x over previous
//
#include <hip/hip_runtime.h>
#include <hip/hip_fp16.h>

#define BLOCK 256

// ---------------- typed vector load/store helpers ----------------
__device__ inline float4 ld4f(const float* p) { return *(const float4*)p; }
__device__ inline float4 ld4f(const __half* p) {
    uint2 u = *(const uint2*)p;
    __half2 a = *reinterpret_cast<__half2*>(&u.x);
    __half2 b = *reinterpret_cast<__half2*>(&u.y);
    float2 fa = __half22float2(a), fb = __half22float2(b);
    return make_float4(fa.x, fa.y, fb.x, fb.y);
}
__device__ inline void st4f(float* p, float4 v) { *(float4*)p = v; }
__device__ inline void st4f(__half* p, float4 v) {
    __half2 a = __floats2half2_rn(v.x, v.y);
    __half2 b = __floats2half2_rn(v.z, v.w);
    uint2 u;
    u.x = *reinterpret_cast<unsigned*>(&a);
    u.y = *reinterpret_cast<unsigned*>(&b);
    *(uint2*)p = u;
}
__device__ inline void st8f(float* p, const float f[8]) {
    *(float4*)p       = make_float4(f[0], f[1], f[2], f[3]);
    *(float4*)(p + 4) = make_float4(f[4], f[5], f[6], f[7]);
}
__device__ inline void st8f(__half* p, const float f[8]) {
    union { __half2 h[4]; float4 v; } u;
    u.h[0] = __floats2half2_rn(f[0], f[1]);
    u.h[1] = __floats2half2_rn(f[2], f[3]);
    u.h[2] = __floats2half2_rn(f[4], f[5]);
    u.h[3] = __floats2half2_rn(f[6], f[7]);
    *(float4*)p = u.v;
}

// ---------------- degree ----------------
__global__ void deg_kernel(const int* __restrict__ src, const int* __restrict__ dst,
                           float* __restrict__ degO, float* __restrict__ degI, int E) {
    int e = blockIdx.x * blockDim.x + threadIdx.x;
    if (e < E) {
        atomicAdd(&degO[src[e]], 1.0f);
        atomicAdd(&degI[dst[e]], 1.0f);
    }
}

__global__ void norm_kernel(float* __restrict__ d, int n) {
    int i = blockIdx.x * blockDim.x + threadIdx.x;
    if (i < n) d[i] = rsqrtf(fmaxf(d[i], 1.0f));
}

// ---------------- hierarchical exclusive scan of degI ----------------
__global__ void scan_local(const float* __restrict__ deg, int* __restrict__ rowStart,
                           int* __restrict__ blockSums, int N) {
    __shared__ int tmp[1024];
    int tid = threadIdx.x;
    int i = blockIdx.x * 1024 + tid;
    int v = (i < N) ? (int)deg[i] : 0;
    tmp[tid] = v;
    __syncthreads();
    for (int off = 1; off < 1024; off <<= 1) {
        int t = (tid >= off) ? tmp[tid - off] : 0;
        __syncthreads();
        tmp[tid] += t;
        __syncthreads();
    }
    if (i < N) rowStart[i] = tmp[tid] - v;
    if (tid == 0) blockSums[blockIdx.x] = tmp[1023];
}

__global__ void scan_sums(int* __restrict__ blockSums, int nb) {
    __shared__ int tmp[64];
    int tid = threadIdx.x;
    int v = (tid < nb) ? blockSums[tid] : 0;
    tmp[tid] = v;
    __syncthreads();
    for (int off = 1; off < 64; off <<= 1) {
        int t = (tid >= off) ? tmp[tid - off] : 0;
        __syncthreads();
        tmp[tid] += t;
        __syncthreads();
    }
    if (tid < nb) blockSums[tid] = tmp[tid] - v;
}

__global__ void scan_add(int* __restrict__ rowStart, const int* __restrict__ blockSums,
                         int N, int E) {
    int i = blockIdx.x * blockDim.x + threadIdx.x;
    if (i < N) rowStart[i] += blockSums[i >> 10];
    if (i == N) rowStart[N] = E;
}

__global__ void copy_int_kernel(const int* __restrict__ a, int* __restrict__ b, int n) {
    int i = blockIdx.x * blockDim.x + threadIdx.x;
    if (i < n) b[i] = a[i];
}

// ---------------- permute edges into dst-sorted order ----------------
__global__ void permute_kernel(const int* __restrict__ src, const int* __restrict__ dst,
                               const float* __restrict__ efet, int* __restrict__ cursor,
                               int* __restrict__ srcSorted, float* __restrict__ wSorted, int E) {
    int e = blockIdx.x * blockDim.x + threadIdx.x;
    if (e < E) {
        int d = dst[e];
        int p = atomicAdd(&cursor[d], 1);
        srcSorted[p] = src[e];
        wSorted[p] = efet[e];
    }
}

// ---------------- CSR gather-aggregation, fused epilogue, 4x unrolled ----------------
template <int D, typename IT, typename OT>
__global__ void agg_kernel(const IT* __restrict__ in, OT* __restrict__ out,
                           const int* __restrict__ rowStart, const int* __restrict__ srcSorted,
                           const float* __restrict__ wSorted,    // null -> 1
                           const float* __restrict__ srcScale,   // null -> 1
                           const float* __restrict__ dstScale,   // null -> skip scale+bias
                           const float* __restrict__ bias,
                           int N, int relu) {
    constexpr int TPN = D / 4;   // threads per node, 4 cols each
    int gid = blockIdx.x * blockDim.x + threadIdx.x;
    int v = gid / TPN;
    int c4 = (gid % TPN) * 4;
    if (v >= N) return;
    int beg = rowStart[v], end = rowStart[v + 1];
    float ax = 0.f, ay = 0.f, az = 0.f, aw = 0.f;
    const IT* base = in + c4;

    int j = beg;
    for (; j + 4 <= end; j += 4) {
        int s0 = srcSorted[j + 0], s1 = srcSorted[j + 1];
        int s2 = srcSorted[j + 2], s3 = srcSorted[j + 3];
        float w0 = 1.f, w1 = 1.f, w2 = 1.f, w3 = 1.f;
        if (wSorted) {
            w0 = wSorted[j + 0]; w1 = wSorted[j + 1];
            w2 = wSorted[j + 2]; w3 = wSorted[j + 3];
        }
        if (srcScale) {
            w0 *= srcScale[s0]; w1 *= srcScale[s1];
            w2 *= srcScale[s2]; w3 *= srcScale[s3];
        }
        float4 x0 = ld4f(base + (size_t)s0 * D);
        float4 x1 = ld4f(base + (size_t)s1 * D);
        float4 x2 = ld4f(base + (size_t)s2 * D);
        float4 x3 = ld4f(base + (size_t)s3 * D);
        ax += x0.x * w0; ay += x0.y * w0; az += x0.z * w0; aw += x0.w * w0;
        ax += x1.x * w1; ay += x1.y * w1; az += x1.z * w1; aw += x1.w * w1;
        ax += x2.x * w2; ay += x2.y * w2; az += x2.z * w2; aw += x2.w * w2;
        ax += x3.x * w3; ay += x3.y * w3; az += x3.z * w3; aw += x3.w * w3;
    }
    for (; j < end; ++j) {
        int s = srcSorted[j];
        float w = 1.0f;
        if (wSorted) w = wSorted[j];
        if (srcScale) w *= srcScale[s];
        float4 val = ld4f(base + (size_t)s * D);
        ax += val.x * w; ay += val.y * w; az += val.z * w; aw += val.w * w;
    }
    if (dstScale) {
        float sc = dstScale[v];
        ax = ax * sc + bias[c4 + 0];
        ay = ay * sc + bias[c4 + 1];
        az = az * sc + bias[c4 + 2];
        aw = aw * sc + bias[c4 + 3];
    }
    if (relu) {
        ax = fmaxf(ax, 0.f); ay = fmaxf(ay, 0.f);
        az = fmaxf(az, 0.f); aw = fmaxf(aw, 0.f);
    }
    st4f(out + (size_t)v * D + c4, make_float4(ax, ay, az, aw));
}

// ---------------- tiled register-blocked GEMM ----------------
template <int KT, int RPT, int TN, typename OT>
__global__ __launch_bounds__(256) void gemm_tiled(
    const float* __restrict__ A, const float* __restrict__ W,
    const float* __restrict__ rowScaleIn,   // null -> 1
    const float* __restrict__ rowScaleOut,  // null -> no scale/bias
    const float* __restrict__ bias,
    OT* __restrict__ C, int N, int K1, int relu)
{
    constexpr int NC8 = TN / 8;          // col groups of 8
    constexpr int RT  = 256 / NC8;       // row-threads
    constexpr int TM  = RT * RPT;        // tile rows
    constexpr int AFPT = TM * KT / 256;  // A floats per thread (stage)
    constexpr int WF4  = KT * TN / 1024; // W float4s per thread (stage)

    __shared__ float Alds[KT][TM];
    __shared__ float Wlds[KT][TN];

    const int t    = threadIdx.x;
    const int cg   = t % NC8;
    const int rt   = t / NC8;
    const int c0   = cg * 8;
    const int row0 = blockIdx.x * TM;

    const int arow   = t % TM;
    const int akb    = (t / TM) * AFPT;
    const int arow_g = row0 + arow;
    float rsc = 1.0f;
    if (rowScaleIn && arow_g < N) rsc = rowScaleIn[arow_g];

    float acc[RPT][8];
#pragma unroll
    for (int r = 0; r < RPT; ++r)
#pragma unroll
        for (int j = 0; j < 8; ++j) acc[r][j] = 0.f;

    for (int k0 = 0; k0 < K1; k0 += KT) {
        float av[AFPT];
        if (arow_g < N) {
            const float* ag = A + (size_t)arow_g * K1 + k0 + akb;
            if constexpr (AFPT % 4 == 0) {
#pragma unroll
                for (int j4 = 0; j4 < AFPT; j4 += 4)
                    *(float4*)&av[j4] = *(const float4*)(ag + j4);
            } else {
                *(float2*)&av[0] = *(const float2*)ag;
            }
        } else {
#pragma unroll
            for (int j = 0; j < AFPT; ++j) av[j] = 0.f;
        }
#pragma unroll
        for (int j = 0; j < AFPT; ++j)
            Alds[akb + j][arow] = av[j] * rsc;

        {
            const float4* wg = (const float4*)(W + (size_t)k0 * TN);
            float4* wl = (float4*)&Wlds[0][0];
#pragma unroll
            for (int j = 0; j < WF4; ++j) wl[j * 256 + t] = wg[j * 256 + t];
        }
        __syncthreads();

#pragma unroll
        for (int kk = 0; kk < KT; ++kk) {
            float a[RPT];
            if constexpr (RPT == 4) {
                float4 avv = *(const float4*)&Alds[kk][rt * 4];
                a[0] = avv.x; a[1] = avv.y; a[2] = avv.z; a[3] = avv.w;
            } else if constexpr (RPT == 2) {
                float2 avv = *(const float2*)&Alds[kk][rt * 2];
                a[0] = avv.x; a[1] = avv.y;
            } else {
                a[0] = Alds[kk][rt];
            }
            float4 w0 = *(const float4*)&Wlds[kk][c0];
            float4 w1 = *(const float4*)&Wlds[kk][c0 + 4];
#pragma unroll
            for (int r = 0; r < RPT; ++r) {
                acc[r][0] += a[r] * w0.x; acc[r][1] += a[r] * w0.y;
                acc[r][2] += a[r] * w0.z; acc[r][3] += a[r] * w0.w;
                acc[r][4] += a[r] * w1.x; acc[r][5] += a[r] * w1.y;
                acc[r][6] += a[r] * w1.z; acc[r][7] += a[r] * w1.w;
            }
        }
        __syncthreads();
    }

#pragma unroll
    for (int r = 0; r < RPT; ++r) {
        int row_g = row0 + rt * RPT + r;
        if (row_g >= N) continue;
        float f[8];
        if (rowScaleOut) {
            float sc = rowScaleOut[row_g];
#pragma unroll
            for (int j = 0; j < 8; ++j) f[j] = acc[r][j] * sc + bias[c0 + j];
        } else {
#pragma unroll
            for (int j = 0; j < 8; ++j) f[j] = acc[r][j];
        }
        if (relu) {
#pragma unroll
            for (int j = 0; j < 8; ++j) f[j] = fmaxf(f[j], 0.f);
        }
        st8f(C + (size_t)row_g * TN + c0, f);
    }
}

// ---------------- naive GEMM (kept for K2=4 layer) ----------------
__global__ void gemm_kernel(const float* __restrict__ A, const float* __restrict__ W,
                            const float* __restrict__ rowScaleIn,
                            const float* __restrict__ rowScaleOut,
                            const float* __restrict__ bias,
                            float* __restrict__ C, int N, int K1, int K2, int relu) {
    int gid = blockIdx.x * blockDim.x + threadIdx.x;
    int col = gid % K2;
    int row = gid / K2;
    if (row >= N) return;
    const float* a = A + (size_t)row * K1;
    float acc = 0.0f;
    for (int k = 0; k < K1; ++k) acc += a[k] * W[k * K2 + col];
    if (rowScaleIn) acc *= rowScaleIn[row];
    if (rowScaleOut) acc = acc * rowScaleOut[row] + bias[col];
    if (relu) acc = fmaxf(acc, 0.0f);
    C[gid] = acc;
}

static inline int nblk(long n) { return (int)((n + BLOCK - 1) / BLOCK); }

extern "C" void kernel_launch(void* const* d_in, const int* in_sizes, int n_in,
                              void* d_out, int out_size, void* d_ws, size_t ws_size,
                              hipStream_t stream) {
    const float* x    = (const float*)d_in[0];
    const float* efet = (const float*)d_in[1];
    const int*   src  = (const int*)d_in[2];
    const int*   dst  = (const int*)d_in[3];
    const float* W1 = (const float*)d_in[4];  const float* b1 = (const float*)d_in[5];
    const float* W2 = (const float*)d_in[6];  const float* b2 = (const float*)d_in[7];
    const float* W3 = (const float*)d_in[8];  const float* b3 = (const float*)d_in[9];
    const float* W4 = (const float*)d_in[10]; const float* b4 = (const float*)d_in[11];
    const float* W5 = (const float*)d_in[12]; const float* b5 = (const float*)d_in[13];
    float* out = (float*)d_out;

    const int N = in_sizes[0] / 16;
    const int E = in_sizes[2];
    const int NB1024 = (N + 1023) / 1024;

    // ---- workspace layout (floats) ----
    float* ws       = (float*)d_ws;
    float* normO    = ws;                                  // N
    float* normI    = ws + (size_t)N;                      // N (holds degI pre-norm)
    int*   rowStart = (int*)(ws + 2 * (size_t)N);          // N+1 (pad 4)
    int*   cursor   = (int*)(ws + 3 * (size_t)N + 4);      // N
    int*   blockSums= (int*)(ws + 4 * (size_t)N + 4);      // 64
    int*   srcSorted= (int*)(ws + 4 * (size_t)N + 68);     // E
    float* wSorted  = ws + 4 * (size_t)N + 68 + (size_t)E; // E
    float* buf1     = ws + 4 * (size_t)N + 68 + 2 * (size_t)E;  // 256N floats
    float* buf2     = buf1 + 256 * (size_t)N;                   // 256N floats
    __half* buf2h   = (__half*)buf2;                            // same region as halves

    // ---- degrees + CSR build ----
    hipMemsetAsync(normO, 0, 2 * (size_t)N * sizeof(float), stream);
    deg_kernel<<<nblk(E), BLOCK, 0, stream>>>(src, dst, normO, normI, E);
    scan_local<<<NB1024, 1024, 0, stream>>>(normI, rowStart, blockSums, N);
    scan_sums<<<1, 64, 0, stream>>>(blockSums, NB1024);
    scan_add<<<nblk(N + 1), BLOCK, 0, stream>>>(rowStart, blockSums, N, E);
    copy_int_kernel<<<nblk(N), BLOCK, 0, stream>>>(rowStart, cursor, N);
    permute_kernel<<<nblk(E), BLOCK, 0, stream>>>(src, dst, efet, cursor, srcSorted, wSorted, E);
    norm_kernel<<<nblk(2L * N), BLOCK, 0, stream>>>(normO, 2 * N);

    // ---- Layer 1: agg-first 16-dim (fp32), GEMM 16->256 -> fp16, ewa-agg fp16->fp32 ----
    agg_kernel<16, float, float><<<nblk((long)N * 4), BLOCK, 0, stream>>>(
        x, buf1, rowStart, srcSorted, nullptr, normO, nullptr, nullptr, N, 0);
    gemm_tiled<16, 4, 256, __half><<<(N + 31) / 32, 256, 0, stream>>>(
        buf1, W1, nullptr, normI, b1, buf2h, N, 16, 1);
    agg_kernel<256, __half, float><<<nblk((long)N * 64), BLOCK, 0, stream>>>(
        buf2h, buf1, rowStart, srcSorted, wSorted, nullptr, nullptr, nullptr, N, 1);   // h1 = buf1

    // ---- Layer 2: GEMM 256->128 -> fp16, gc-agg fp16->fp16, ewa-agg fp16->fp32 ----
    gemm_tiled<32, 4, 128, __half><<<(N + 63) / 64, 256, 0, stream>>>(
        buf1, W2, normO, nullptr, nullptr, buf2h, N, 256, 0);
    agg_kernel<128, __half, __half><<<nblk((long)N * 32), BLOCK, 0, stream>>>(
        buf2h, buf2h + 128 * (size_t)N, rowStart, srcSorted, nullptr, nullptr, normI, b2, N, 1);
    agg_kernel<128, __half, float><<<nblk((long)N * 32), BLOCK, 0, stream>>>(
        buf2h + 128 * (size_t)N, buf1, rowStart, srcSorted, wSorted, nullptr, nullptr, nullptr, N, 1); // h2 = buf1

    // ---- Layer 3: GEMM 128->64 -> fp16, gc-agg fp16->fp16, ewa-agg fp16->fp32 ----
    gemm_tiled<32, 2, 64, __half><<<(N + 63) / 64, 256, 0, stream>>>(
        buf1, W3, normO, nullptr, nullptr, buf2h, N, 128, 0);
    agg_kernel<64, __half, __half><<<nblk((long)N * 16), BLOCK, 0, stream>>>(
        buf2h, buf2h + 64 * (size_t)N, rowStart, srcSorted, nullptr, nullptr, normI, b3, N, 1);
    agg_kernel<64, __half, float><<<nblk((long)N * 16), BLOCK, 0, stream>>>(
        buf2h + 64 * (size_t)N, buf1, rowStart, srcSorted, wSorted, nullptr, nullptr, nullptr, N, 1); // h3 = buf1

    // ---- Layer 4: GEMM 64->32 -> fp16, gc-agg fp16->fp32 (h4 feeds naive gemm) ----
    gemm_tiled<32, 1, 32, __half><<<(N + 63) / 64, 256, 0, stream>>>(
        buf1, W4, normO, nullptr, nullptr, buf2h, N, 64, 0);
    agg_kernel<32, __half, float><<<nblk((long)N * 8), BLOCK, 0, stream>>>(
        buf2h, buf1, rowStart, srcSorted, nullptr, nullptr, normI, b4, N, 1);          // h4 = buf1

    // ---- Layer 5: GEMM 32->4 (fp32), gc-agg fp32->out ----
    gemm_kernel<<<nblk((long)N * 4), BLOCK, 0, stream>>>(
        buf1, W5, normO, nullptr, nullptr, buf1 + 32 * (size_t)N, N, 32, 4, 0);
    agg_kernel<4, float, float><<<nblk((long)N * 1), BLOCK, 0, stream>>>(
        buf1 + 32 * (size_t)N, out, rowStart, srcSorted, nullptr, nullptr, normI, b5, N, 0);
}

// Round 6
// 540.046 us; speedup vs baseline: 5.7252x; 1.0475x over previous
//
#include <hip/hip_runtime.h>
#include <hip/hip_fp16.h>

#define BLOCK 256
#define PAD 16   // one counter per 64B cache line

// ---------------- typed vector load/store helpers ----------------
__device__ inline float4 ld4f(const float* p) { return *(const float4*)p; }
__device__ inline float4 ld4f(const __half* p) {
    uint2 u = *(const uint2*)p;
    __half2 a = *reinterpret_cast<__half2*>(&u.x);
    __half2 b = *reinterpret_cast<__half2*>(&u.y);
    float2 fa = __half22float2(a), fb = __half22float2(b);
    return make_float4(fa.x, fa.y, fb.x, fb.y);
}
__device__ inline void st4f(float* p, float4 v) { *(float4*)p = v; }
__device__ inline void st4f(__half* p, float4 v) {
    __half2 a = __floats2half2_rn(v.x, v.y);
    __half2 b = __floats2half2_rn(v.z, v.w);
    uint2 u;
    u.x = *reinterpret_cast<unsigned*>(&a);
    u.y = *reinterpret_cast<unsigned*>(&b);
    *(uint2*)p = u;
}
__device__ inline void st8f(float* p, const float f[8]) {
    *(float4*)p       = make_float4(f[0], f[1], f[2], f[3]);
    *(float4*)(p + 4) = make_float4(f[4], f[5], f[6], f[7]);
}
__device__ inline void st8f(__half* p, const float f[8]) {
    union { __half2 h[4]; float4 v; } u;
    u.h[0] = __floats2half2_rn(f[0], f[1]);
    u.h[1] = __floats2half2_rn(f[2], f[3]);
    u.h[2] = __floats2half2_rn(f[4], f[5]);
    u.h[3] = __floats2half2_rn(f[6], f[7]);
    *(float4*)p = u.v;
}

// ---------------- degree (padded counters, int atomics) ----------------
__global__ void deg_kernel(const int* __restrict__ src, const int* __restrict__ dst,
                           int* __restrict__ degOpad, int* __restrict__ degIpad, int E) {
    int e = blockIdx.x * blockDim.x + threadIdx.x;
    if (e < E) {
        atomicAdd(&degOpad[src[e] * PAD], 1);
        atomicAdd(&degIpad[dst[e] * PAD], 1);
    }
}

__global__ void norm_kernel(const int* __restrict__ degOpad, const int* __restrict__ degIpad,
                            float* __restrict__ normO, float* __restrict__ normI, int N) {
    int i = blockIdx.x * blockDim.x + threadIdx.x;
    if (i < N) {
        normO[i] = rsqrtf(fmaxf((float)degOpad[i * PAD], 1.0f));
        normI[i] = rsqrtf(fmaxf((float)degIpad[i * PAD], 1.0f));
    }
}

// ---------------- hierarchical exclusive scan of degI (padded input) ----------------
__global__ void scan_local(const int* __restrict__ degIpad, int* __restrict__ rowStart,
                           int* __restrict__ blockSums, int N) {
    __shared__ int tmp[1024];
    int tid = threadIdx.x;
    int i = blockIdx.x * 1024 + tid;
    int v = (i < N) ? degIpad[i * PAD] : 0;
    tmp[tid] = v;
    __syncthreads();
    for (int off = 1; off < 1024; off <<= 1) {
        int t = (tid >= off) ? tmp[tid - off] : 0;
        __syncthreads();
        tmp[tid] += t;
        __syncthreads();
    }
    if (i < N) rowStart[i] = tmp[tid] - v;
    if (tid == 0) blockSums[blockIdx.x] = tmp[1023];
}

__global__ void scan_sums(int* __restrict__ blockSums, int nb) {
    __shared__ int tmp[64];
    int tid = threadIdx.x;
    int v = (tid < nb) ? blockSums[tid] : 0;
    tmp[tid] = v;
    __syncthreads();
    for (int off = 1; off < 64; off <<= 1) {
        int t = (tid >= off) ? tmp[tid - off] : 0;
        __syncthreads();
        tmp[tid] += t;
        __syncthreads();
    }
    if (tid < nb) blockSums[tid] = tmp[tid] - v;
}

// finalize rowStart and init padded cursor
__global__ void scan_add(int* __restrict__ rowStart, const int* __restrict__ blockSums,
                         int* __restrict__ cursorPad, int N, int E) {
    int i = blockIdx.x * blockDim.x + threadIdx.x;
    if (i < N) {
        int r = rowStart[i] + blockSums[i >> 10];
        rowStart[i] = r;
        cursorPad[i * PAD] = r;
    }
    if (i == N) rowStart[N] = E;
}

// ---------------- permute edges into dst-sorted order (padded cursor) ----------------
__global__ void permute_kernel(const int* __restrict__ src, const int* __restrict__ dst,
                               const float* __restrict__ efet, int* __restrict__ cursorPad,
                               int* __restrict__ srcSorted, float* __restrict__ wSorted, int E) {
    int e = blockIdx.x * blockDim.x + threadIdx.x;
    if (e < E) {
        int d = dst[e];
        int p = atomicAdd(&cursorPad[d * PAD], 1);
        srcSorted[p] = src[e];
        wSorted[p] = efet[e];
    }
}

// ---------------- CSR gather-aggregation, fused epilogue, 4x unrolled ----------------
template <int D, typename IT, typename OT>
__global__ void agg_kernel(const IT* __restrict__ in, OT* __restrict__ out,
                           const int* __restrict__ rowStart, const int* __restrict__ srcSorted,
                           const float* __restrict__ wSorted,    // null -> 1
                           const float* __restrict__ srcScale,   // null -> 1
                           const float* __restrict__ dstScale,   // null -> skip scale+bias
                           const float* __restrict__ bias,
                           int N, int relu) {
    constexpr int TPN = D / 4;   // threads per node, 4 cols each
    int gid = blockIdx.x * blockDim.x + threadIdx.x;
    int v = gid / TPN;
    int c4 = (gid % TPN) * 4;
    if (v >= N) return;
    int beg = rowStart[v], end = rowStart[v + 1];
    float ax = 0.f, ay = 0.f, az = 0.f, aw = 0.f;
    const IT* base = in + c4;

    int j = beg;
    for (; j + 4 <= end; j += 4) {
        int s0 = srcSorted[j + 0], s1 = srcSorted[j + 1];
        int s2 = srcSorted[j + 2], s3 = srcSorted[j + 3];
        float w0 = 1.f, w1 = 1.f, w2 = 1.f, w3 = 1.f;
        if (wSorted) {
            w0 = wSorted[j + 0]; w1 = wSorted[j + 1];
            w2 = wSorted[j + 2]; w3 = wSorted[j + 3];
        }
        if (srcScale) {
            w0 *= srcScale[s0]; w1 *= srcScale[s1];
            w2 *= srcScale[s2]; w3 *= srcScale[s3];
        }
        float4 x0 = ld4f(base + (size_t)s0 * D);
        float4 x1 = ld4f(base + (size_t)s1 * D);
        float4 x2 = ld4f(base + (size_t)s2 * D);
        float4 x3 = ld4f(base + (size_t)s3 * D);
        ax += x0.x * w0; ay += x0.y * w0; az += x0.z * w0; aw += x0.w * w0;
        ax += x1.x * w1; ay += x1.y * w1; az += x1.z * w1; aw += x1.w * w1;
        ax += x2.x * w2; ay += x2.y * w2; az += x2.z * w2; aw += x2.w * w2;
        ax += x3.x * w3; ay += x3.y * w3; az += x3.z * w3; aw += x3.w * w3;
    }
    for (; j < end; ++j) {
        int s = srcSorted[j];
        float w = 1.0f;
        if (wSorted) w = wSorted[j];
        if (srcScale) w *= srcScale[s];
        float4 val = ld4f(base + (size_t)s * D);
        ax += val.x * w; ay += val.y * w; az += val.z * w; aw += val.w * w;
    }
    if (dstScale) {
        float sc = dstScale[v];
        ax = ax * sc + bias[c4 + 0];
        ay = ay * sc + bias[c4 + 1];
        az = az * sc + bias[c4 + 2];
        aw = aw * sc + bias[c4 + 3];
    }
    if (relu) {
        ax = fmaxf(ax, 0.f); ay = fmaxf(ay, 0.f);
        az = fmaxf(az, 0.f); aw = fmaxf(aw, 0.f);
    }
    st4f(out + (size_t)v * D + c4, make_float4(ax, ay, az, aw));
}

// ---------------- tiled register-blocked GEMM ----------------
template <int KT, int RPT, int TN, typename OT>
__global__ __launch_bounds__(256) void gemm_tiled(
    const float* __restrict__ A, const float* __restrict__ W,
    const float* __restrict__ rowScaleIn,   // null -> 1
    const float* __restrict__ rowScaleOut,  // null -> no scale/bias
    const float* __restrict__ bias,
    OT* __restrict__ C, int N, int K1, int relu)
{
    constexpr int NC8 = TN / 8;          // col groups of 8
    constexpr int RT  = 256 / NC8;       // row-threads
    constexpr int TM  = RT * RPT;        // tile rows
    constexpr int AFPT = TM * KT / 256;  // A floats per thread (stage)
    constexpr int WF4  = KT * TN / 1024; // W float4s per thread (stage)

    __shared__ float Alds[KT][TM];
    __shared__ float Wlds[KT][TN];

    const int t    = threadIdx.x;
    const int cg   = t % NC8;
    const int rt   = t / NC8;
    const int c0   = cg * 8;
    const int row0 = blockIdx.x * TM;

    const int arow   = t % TM;
    const int akb    = (t / TM) * AFPT;
    const int arow_g = row0 + arow;
    float rsc = 1.0f;
    if (rowScaleIn && arow_g < N) rsc = rowScaleIn[arow_g];

    float acc[RPT][8];
#pragma unroll
    for (int r = 0; r < RPT; ++r)
#pragma unroll
        for (int j = 0; j < 8; ++j) acc[r][j] = 0.f;

    for (int k0 = 0; k0 < K1; k0 += KT) {
        float av[AFPT];
        if (arow_g < N) {
            const float* ag = A + (size_t)arow_g * K1 + k0 + akb;
            if constexpr (AFPT % 4 == 0) {
#pragma unroll
                for (int j4 = 0; j4 < AFPT; j4 += 4)
                    *(float4*)&av[j4] = *(const float4*)(ag + j4);
            } else {
                *(float2*)&av[0] = *(const float2*)ag;
            }
        } else {
#pragma unroll
            for (int j = 0; j < AFPT; ++j) av[j] = 0.f;
        }
#pragma unroll
        for (int j = 0; j < AFPT; ++j)
            Alds[akb + j][arow] = av[j] * rsc;

        {
            const float4* wg = (const float4*)(W + (size_t)k0 * TN);
            float4* wl = (float4*)&Wlds[0][0];
#pragma unroll
            for (int j = 0; j < WF4; ++j) wl[j * 256 + t] = wg[j * 256 + t];
        }
        __syncthreads();

#pragma unroll
        for (int kk = 0; kk < KT; ++kk) {
            float a[RPT];
            if constexpr (RPT == 4) {
                float4 avv = *(const float4*)&Alds[kk][rt * 4];
                a[0] = avv.x; a[1] = avv.y; a[2] = avv.z; a[3] = avv.w;
            } else if constexpr (RPT == 2) {
                float2 avv = *(const float2*)&Alds[kk][rt * 2];
                a[0] = avv.x; a[1] = avv.y;
            } else {
                a[0] = Alds[kk][rt];
            }
            float4 w0 = *(const float4*)&Wlds[kk][c0];
            float4 w1 = *(const float4*)&Wlds[kk][c0 + 4];
#pragma unroll
            for (int r = 0; r < RPT; ++r) {
                acc[r][0] += a[r] * w0.x; acc[r][1] += a[r] * w0.y;
                acc[r][2] += a[r] * w0.z; acc[r][3] += a[r] * w0.w;
                acc[r][4] += a[r] * w1.x; acc[r][5] += a[r] * w1.y;
                acc[r][6] += a[r] * w1.z; acc[r][7] += a[r] * w1.w;
            }
        }
        __syncthreads();
    }

#pragma unroll
    for (int r = 0; r < RPT; ++r) {
        int row_g = row0 + rt * RPT + r;
        if (row_g >= N) continue;
        float f[8];
        if (rowScaleOut) {
            float sc = rowScaleOut[row_g];
#pragma unroll
            for (int j = 0; j < 8; ++j) f[j] = acc[r][j] * sc + bias[c0 + j];
        } else {
#pragma unroll
            for (int j = 0; j < 8; ++j) f[j] = acc[r][j];
        }
        if (relu) {
#pragma unroll
            for (int j = 0; j < 8; ++j) f[j] = fmaxf(f[j], 0.f);
        }
        st8f(C + (size_t)row_g * TN + c0, f);
    }
}

// ---------------- naive GEMM (kept for K2=4 layer) ----------------
__global__ void gemm_kernel(const float* __restrict__ A, const float* __restrict__ W,
                            const float* __restrict__ rowScaleIn,
                            const float* __restrict__ rowScaleOut,
                            const float* __restrict__ bias,
                            float* __restrict__ C, int N, int K1, int K2, int relu) {
    int gid = blockIdx.x * blockDim.x + threadIdx.x;
    int col = gid % K2;
    int row = gid / K2;
    if (row >= N) return;
    const float* a = A + (size_t)row * K1;
    float acc = 0.0f;
    for (int k = 0; k < K1; ++k) acc += a[k] * W[k * K2 + col];
    if (rowScaleIn) acc *= rowScaleIn[row];
    if (rowScaleOut) acc = acc * rowScaleOut[row] + bias[col];
    if (relu) acc = fmaxf(acc, 0.0f);
    C[gid] = acc;
}

static inline int nblk(long n) { return (int)((n + BLOCK - 1) / BLOCK); }

extern "C" void kernel_launch(void* const* d_in, const int* in_sizes, int n_in,
                              void* d_out, int out_size, void* d_ws, size_t ws_size,
                              hipStream_t stream) {
    const float* x    = (const float*)d_in[0];
    const float* efet = (const float*)d_in[1];
    const int*   src  = (const int*)d_in[2];
    const int*   dst  = (const int*)d_in[3];
    const float* W1 = (const float*)d_in[4];  const float* b1 = (const float*)d_in[5];
    const float* W2 = (const float*)d_in[6];  const float* b2 = (const float*)d_in[7];
    const float* W3 = (const float*)d_in[8];  const float* b3 = (const float*)d_in[9];
    const float* W4 = (const float*)d_in[10]; const float* b4 = (const float*)d_in[11];
    const float* W5 = (const float*)d_in[12]; const float* b5 = (const float*)d_in[13];
    float* out = (float*)d_out;

    const int N = in_sizes[0] / 16;
    const int E = in_sizes[2];
    const int NB1024 = (N + 1023) / 1024;

    // ---- workspace layout (float units) ----
    float* ws        = (float*)d_ws;
    float* normO     = ws;                                   // N
    float* normI     = ws + (size_t)N;                       // N
    int*   rowStart  = (int*)(ws + 2 * (size_t)N);           // N+4
    int*   blockSums = (int*)(ws + 3 * (size_t)N + 4);       // 64
    int*   srcSorted = (int*)(ws + 3 * (size_t)N + 68);      // E
    float* wSorted   = ws + 3 * (size_t)N + 68 + (size_t)E;  // E
    int*   degOpad   = (int*)(ws + 3 * (size_t)N + 68 + 2 * (size_t)E); // 16N
    int*   degIpad   = degOpad + (size_t)PAD * N;            // 16N
    int*   cursorPad = degIpad + (size_t)PAD * N;            // 16N
    float* buf1      = (float*)(cursorPad + (size_t)PAD * N);// 256N floats
    float* buf2      = buf1 + 256 * (size_t)N;               // 256N floats
    __half* buf2h    = (__half*)buf2;

    // ---- degrees + CSR build ----
    hipMemsetAsync(degOpad, 0, 2 * (size_t)PAD * N * sizeof(int), stream);
    deg_kernel<<<nblk(E), BLOCK, 0, stream>>>(src, dst, degOpad, degIpad, E);
    scan_local<<<NB1024, 1024, 0, stream>>>(degIpad, rowStart, blockSums, N);
    scan_sums<<<1, 64, 0, stream>>>(blockSums, NB1024);
    scan_add<<<nblk(N + 1), BLOCK, 0, stream>>>(rowStart, blockSums, cursorPad, N, E);
    permute_kernel<<<nblk(E), BLOCK, 0, stream>>>(src, dst, efet, cursorPad, srcSorted, wSorted, E);
    norm_kernel<<<nblk(N), BLOCK, 0, stream>>>(degOpad, degIpad, normO, normI, N);

    // ---- Layer 1: agg-first 16-dim (fp32), GEMM 16->256 -> fp16, ewa-agg fp16->fp32 ----
    agg_kernel<16, float, float><<<nblk((long)N * 4), BLOCK, 0, stream>>>(
        x, buf1, rowStart, srcSorted, nullptr, normO, nullptr, nullptr, N, 0);
    gemm_tiled<16, 4, 256, __half><<<(N + 31) / 32, 256, 0, stream>>>(
        buf1, W1, nullptr, normI, b1, buf2h, N, 16, 1);
    agg_kernel<256, __half, float><<<nblk((long)N * 64), BLOCK, 0, stream>>>(
        buf2h, buf1, rowStart, srcSorted, wSorted, nullptr, nullptr, nullptr, N, 1);   // h1 = buf1

    // ---- Layer 2: GEMM 256->128 -> fp16, gc-agg fp16->fp16, ewa-agg fp16->fp32 ----
    gemm_tiled<32, 4, 128, __half><<<(N + 63) / 64, 256, 0, stream>>>(
        buf1, W2, normO, nullptr, nullptr, buf2h, N, 256, 0);
    agg_kernel<128, __half, __half><<<nblk((long)N * 32), BLOCK, 0, stream>>>(
        buf2h, buf2h + 128 * (size_t)N, rowStart, srcSorted, nullptr, nullptr, normI, b2, N, 1);
    agg_kernel<128, __half, float><<<nblk((long)N * 32), BLOCK, 0, stream>>>(
        buf2h + 128 * (size_t)N, buf1, rowStart, srcSorted, wSorted, nullptr, nullptr, nullptr, N, 1); // h2 = buf1

    // ---- Layer 3: GEMM 128->64 -> fp16, gc-agg fp16->fp16, ewa-agg fp16->fp32 ----
    gemm_tiled<32, 2, 64, __half><<<(N + 63) / 64, 256, 0, stream>>>(
        buf1, W3, normO, nullptr, nullptr, buf2h, N, 128, 0);
    agg_kernel<64, __half, __half><<<nblk((long)N * 16), BLOCK, 0, stream>>>(
        buf2h, buf2h + 64 * (size_t)N, rowStart, srcSorted, nullptr, nullptr, normI, b3, N, 1);
    agg_kernel<64, __half, float><<<nblk((long)N * 16), BLOCK, 0, stream>>>(
        buf2h + 64 * (size_t)N, buf1, rowStart, srcSorted, wSorted, nullptr, nullptr, nullptr, N, 1); // h3 = buf1

    // ---- Layer 4: GEMM 64->32 -> fp16, gc-agg fp16->fp32 (h4 feeds naive gemm) ----
    gemm_tiled<32, 1, 32, __half><<<(N + 63) / 64, 256, 0, stream>>>(
        buf1, W4, normO, nullptr, nullptr, buf2h, N, 64, 0);
    agg_kernel<32, __half, float><<<nblk((long)N * 8), BLOCK, 0, stream>>>(
        buf2h, buf1, rowStart, srcSorted, nullptr, nullptr, normI, b4, N, 1);          // h4 = buf1

    // ---- Layer 5: GEMM 32->4 (fp32), gc-agg fp32->out ----
    gemm_kernel<<<nblk((long)N * 4), BLOCK, 0, stream>>>(
        buf1, W5, normO, nullptr, nullptr, buf1 + 32 * (size_t)N, N, 32, 4, 0);
    agg_kernel<4, float, float><<<nblk((long)N * 1), BLOCK, 0, stream>>>(
        buf1 + 32 * (size_t)N, out, rowStart, srcSorted, nullptr, nullptr, normI, b5, N, 0);
}